// Round 3
// baseline (36.211 us; speedup 1.0000x reference)
//
#include <hip/hip_runtime.h>

// Problem constants (fixed by reference setup_inputs): D=32 detectors,
// in_s = out_s = 64, row stride 2048 floats, B = 8192.
#define NDET    32
#define SEG     64
#define ROWLEN  2048
#define ITERS   2
#define THREADS 256
#define ROWS_PER_BLOCK (ITERS * 64)   // 4 waves * 16 rows * ITERS = 128

typedef __bf16 bf16x8 __attribute__((ext_vector_type(8)));
typedef float  f32x4  __attribute__((ext_vector_type(4)));

__device__ __forceinline__ bf16x8 cvt8(f32x4 a, f32x4 b) {
  bf16x8 r;
  r[0] = (__bf16)a[0]; r[1] = (__bf16)a[1]; r[2] = (__bf16)a[2]; r[3] = (__bf16)a[3];
  r[4] = (__bf16)b[0]; r[5] = (__bf16)b[1]; r[6] = (__bf16)b[2]; r[7] = (__bf16)b[3];
  return r;
}

// y[b, d*64+o] = sum_i x[b, d*64+i] * W[d*64+o, d*64+i]
// Swapped-operand MFMA: D[o][b] = W_tile · x_tile^T  via mfma(A=W, B=x).
// A-frag: lane holds W[dbase + g*16 + (lane&15)][dbase + kh*32 + (lane>>4)*8 + j]
// B-frag: lane holds x[brow + (lane&15)][i = kh*32 + (lane>>4)*8 + j]
// C/D:    lane holds D[row=(lane>>4)*4+r][col=lane&15] -> y[brow+(lane&15)]
//         [dbase + g*16 + (lane>>4)*4 + r]  => one float4 store per g.
__global__ __launch_bounds__(THREADS) void ensemble_linear_mfma(
    const float* __restrict__ x, const float* __restrict__ W,
    float* __restrict__ y) {
  const int d     = blockIdx.y;
  const int lane  = threadIdx.x & 63;
  const int wid   = threadIdx.x >> 6;   // 0..3
  const int row16 = lane & 15;
  const int kgrp  = lane >> 4;          // 0..3
  const int dbase = d * SEG;

  // --- A fragments (W_d rows) straight into registers: 4 o-groups x 2 k-halves ---
  bf16x8 wfrag[4][2];
#pragma unroll
  for (int g = 0; g < 4; ++g) {
    const float* wp = W + (size_t)(dbase + g * 16 + row16) * ROWLEN + dbase + kgrp * 8;
#pragma unroll
    for (int kh = 0; kh < 2; ++kh) {
      f32x4 w0 = *(const f32x4*)(wp + kh * 32);
      f32x4 w1 = *(const f32x4*)(wp + kh * 32 + 4);
      wfrag[g][kh] = cvt8(w0, w1);
    }
  }

  const int b0 = blockIdx.x * ROWS_PER_BLOCK;
#pragma unroll
  for (int it = 0; it < ITERS; ++it) {
    const int brow = b0 + it * 64 + wid * 16;

    // B fragments (x rows): 4 coalesced float4 loads covering 64 floats/row
    const float* xp = x + (size_t)(brow + row16) * ROWLEN + dbase + kgrp * 8;
    f32x4 x0 = *(const f32x4*)(xp);
    f32x4 x1 = *(const f32x4*)(xp + 4);
    f32x4 x2 = *(const f32x4*)(xp + 32);
    f32x4 x3 = *(const f32x4*)(xp + 36);
    bf16x8 a0 = cvt8(x0, x1);   // k = kgrp*8 + 0..7
    bf16x8 a1 = cvt8(x2, x3);   // k = 32 + kgrp*8 + 0..7

    // D[o][b] accumulate, then one float4 store per o-group
    float* yp = y + (size_t)(brow + row16) * ROWLEN + dbase + kgrp * 4;
#pragma unroll
    for (int g = 0; g < 4; ++g) {
      f32x4 acc = (f32x4){0.f, 0.f, 0.f, 0.f};
      acc = __builtin_amdgcn_mfma_f32_16x16x32_bf16(wfrag[g][0], a0, acc, 0, 0, 0);
      acc = __builtin_amdgcn_mfma_f32_16x16x32_bf16(wfrag[g][1], a1, acc, 0, 0, 0);
      *(f32x4*)(yp + g * 16) = acc;
    }
  }
}

extern "C" void kernel_launch(void* const* d_in, const int* in_sizes, int n_in,
                              void* d_out, int out_size, void* d_ws, size_t ws_size,
                              hipStream_t stream) {
  const float* x = (const float*)d_in[0];
  const float* W = (const float*)d_in[1];
  float* y = (float*)d_out;
  const int B = in_sizes[0] / ROWLEN;   // 8192
  dim3 grid(B / ROWS_PER_BLOCK, NDET);
  ensemble_linear_mfma<<<grid, dim3(THREADS), 0, stream>>>(x, W, y);
}

// Round 4
// 28.458 us; speedup vs baseline: 1.2725x; 1.2725x over previous
//
#include <hip/hip_runtime.h>

// Problem constants (fixed by reference setup_inputs): D=32 detectors,
// in_s = out_s = 64, row stride 2048 floats, B = 8192.
#define NDET    32
#define SEG     64
#define ROWLEN  2048
#define TILE_B  128
#define THREADS 256
#define LSTRIDE 72   // LDS row stride in bf16 (144 B, 16B-aligned, padded)

typedef __bf16 bf16x8 __attribute__((ext_vector_type(8)));
typedef __bf16 bf16x4 __attribute__((ext_vector_type(4)));
typedef float  f32x4  __attribute__((ext_vector_type(4)));

__device__ __forceinline__ bf16x4 cvt4(f32x4 a) {
  bf16x4 r;
  r[0] = (__bf16)a[0]; r[1] = (__bf16)a[1]; r[2] = (__bf16)a[2]; r[3] = (__bf16)a[3];
  return r;
}

// y[b, d*64+o] = sum_i x[b, d*64+i] * W[d*64+o, d*64+i]
//
// Staging (coalesced optimum): per load instruction, lane -> row (lane>>4),
// bytes (lane&15)*16 -> each 16-lane group reads one COMPLETE 256B row
// window (4 rows / 8 cache lines per instruction). LDS round-trip performs
// the transpose into MFMA fragment layout.
//
// Compute (r3-verified swapped MFMA): D = W_tile . x_tile^T via
// mfma_f32_16x16x32_bf16(A=W, B=x); lane stores y[brow+(lane&15)]
// [dbase + g*16 + (lane>>4)*4 .. +3] as one float4.
__global__ __launch_bounds__(THREADS) void ensemble_linear_v4(
    const float* __restrict__ x, const float* __restrict__ W,
    float* __restrict__ y) {
  const int d     = blockIdx.y;
  const int b0    = blockIdx.x * TILE_B;
  const int t     = threadIdx.x;
  const int lane  = t & 63;
  const int wid   = t >> 6;        // 0..3
  const int dbase = d * SEG;

  const int rq  = lane >> 4;       // staging: row within 4-row quad
  const int c4  = lane & 15;       // staging: 16B chunk within 256B row

  __shared__ __bf16 wls[SEG * LSTRIDE];      //  9216 B
  __shared__ __bf16 xls[TILE_B * LSTRIDE];   // 18432 B

  // ---- issue ALL global loads up front (12 independent 1KB instrs/wave) ----
  f32x4 wv[4];                     // W rows wid*16 + p*4 + rq
#pragma unroll
  for (int p = 0; p < 4; ++p) {
    const int row = wid * 16 + p * 4 + rq;
    wv[p] = *(const f32x4*)(W + (size_t)(dbase + row) * ROWLEN + dbase + c4 * 4);
  }
  f32x4 xv[8];                     // x rows b0 + wid*32 + p*4 + rq
#pragma unroll
  for (int p = 0; p < 8; ++p) {
    const int row = wid * 32 + p * 4 + rq;
    xv[p] = *(const f32x4*)(x + (size_t)(b0 + row) * ROWLEN + dbase + c4 * 4);
  }

  // ---- convert + stage to LDS ----
#pragma unroll
  for (int p = 0; p < 4; ++p) {
    const int row = wid * 16 + p * 4 + rq;
    *(bf16x4*)(&wls[row * LSTRIDE + c4 * 4]) = cvt4(wv[p]);
  }
#pragma unroll
  for (int p = 0; p < 8; ++p) {
    const int row = wid * 32 + p * 4 + rq;
    *(bf16x4*)(&xls[row * LSTRIDE + c4 * 4]) = cvt4(xv[p]);
  }

  __syncthreads();   // the only barrier

  // ---- fragment reads ----
  const int m16 = lane & 15;       // fragment M/N index
  const int kg  = lane >> 4;       // fragment k-group

  bf16x8 wfrag[4][2];
#pragma unroll
  for (int g = 0; g < 4; ++g)
#pragma unroll
    for (int kh = 0; kh < 2; ++kh)
      wfrag[g][kh] = *(const bf16x8*)(&wls[(g * 16 + m16) * LSTRIDE + kh * 32 + kg * 8]);

  // ---- compute: wave owns rows [wid*32, wid*32+32), 2 sub-tiles of 16 ----
#pragma unroll
  for (int s = 0; s < 2; ++s) {
    const int rbase = wid * 32 + s * 16;
    bf16x8 a0 = *(const bf16x8*)(&xls[(rbase + m16) * LSTRIDE + kg * 8]);        // k 0..31
    bf16x8 a1 = *(const bf16x8*)(&xls[(rbase + m16) * LSTRIDE + 32 + kg * 8]);   // k 32..63

    float* yp = y + (size_t)(b0 + rbase + m16) * ROWLEN + dbase + kg * 4;
#pragma unroll
    for (int g = 0; g < 4; ++g) {
      f32x4 acc = (f32x4){0.f, 0.f, 0.f, 0.f};
      acc = __builtin_amdgcn_mfma_f32_16x16x32_bf16(wfrag[g][0], a0, acc, 0, 0, 0);
      acc = __builtin_amdgcn_mfma_f32_16x16x32_bf16(wfrag[g][1], a1, acc, 0, 0, 0);
      *(f32x4*)(yp + g * 16) = acc;
    }
  }
}

extern "C" void kernel_launch(void* const* d_in, const int* in_sizes, int n_in,
                              void* d_out, int out_size, void* d_ws, size_t ws_size,
                              hipStream_t stream) {
  const float* x = (const float*)d_in[0];
  const float* W = (const float*)d_in[1];
  float* y = (float*)d_out;
  const int B = in_sizes[0] / ROWLEN;   // 8192
  dim3 grid(B / TILE_B, NDET);
  ensemble_linear_v4<<<grid, dim3(THREADS), 0, stream>>>(x, W, y);
}